// Round 8
// baseline (456.114 us; speedup 1.0000x reference)
//
#include <hip/hip_runtime.h>
#include <hip/hip_bf16.h>

#define B_ 8
#define T_ 8192
#define HID_ 256
#define C_ 5
#define K_ 16
#define NC_ 128   // chunks per batch
#define CPB 4     // chunks per block (chunk_kernel)
#define NTILE 32  // 256-position tiles per batch (cumsum pipeline)
#define WIN 80    // 16 pre-window + LMAX(64)
#define WPAD 84
#define NFW 63    // forward-chain matrices k=0..62; backward: R(127), 126..63

__device__ __forceinline__ float gelu_tanh(float x) {
    float u = 0.7978845608028654f * (x + 0.044715f * x * x * x);
    float e = __expf(2.0f * u);
    float th = 1.0f - 2.0f / (e + 1.0f);
    return 0.5f * x * (1.0f + th);
}

__device__ __forceinline__ float bf16lo(unsigned int u) {
    return __uint_as_float(u << 16);
}
__device__ __forceinline__ float bf16hi(unsigned int u) {
    return __uint_as_float(u & 0xffff0000u);
}

// ---------------- Kernel A: encoder (hidden split) -> emitA/emitB + per-tile class sums ----------------
__global__ __launch_bounds__(256) void encoder_kernel(
    const float* __restrict__ seq, const float* __restrict__ W_enc,
    const float* __restrict__ b_enc, const float* __restrict__ W_proj,
    const float* __restrict__ b_proj, float* __restrict__ emitA,
    float* __restrict__ emitB, float* __restrict__ PA)
{
    __shared__ float4 we[128];
    __shared__ float  be[128];
    __shared__ float  wp[128 * C_];
    __shared__ float  prd[4][C_];
    int tid = threadIdx.x;
    int half = blockIdx.x >> 8;
    int blk  = blockIdx.x & 255;
    int h0 = half * 128;
    if (tid < 128) {
        int h = h0 + tid;
        we[tid] = make_float4(W_enc[0*HID_+h], W_enc[1*HID_+h], W_enc[2*HID_+h], W_enc[3*HID_+h]);
        be[tid] = b_enc[h];
    }
    for (int i = tid; i < 128 * C_; i += 256) wp[i] = W_proj[h0 * C_ + i];
    __syncthreads();
    int b = blk >> 5;
    int tile = blk & 31;
    int t = tile * 256 + tid;
    float4 s = reinterpret_cast<const float4*>(seq)[(size_t)b * T_ + t];
    float a0, a1, a2, a3, a4;
    if (half == 0) { a0 = b_proj[0]; a1 = b_proj[1]; a2 = b_proj[2]; a3 = b_proj[3]; a4 = b_proj[4]; }
    else           { a0 = a1 = a2 = a3 = a4 = 0.0f; }
    #pragma unroll 8
    for (int h = 0; h < 128; ++h) {
        float4 w = we[h];
        float pre = be[h] + s.x*w.x + s.y*w.y + s.z*w.z + s.w*w.w;
        float hd = gelu_tanh(pre);
        a0 = fmaf(hd, wp[h*C_+0], a0);
        a1 = fmaf(hd, wp[h*C_+1], a1);
        a2 = fmaf(hd, wp[h*C_+2], a2);
        a3 = fmaf(hd, wp[h*C_+3], a3);
        a4 = fmaf(hd, wp[h*C_+4], a4);
    }
    float* em = half ? emitB : emitA;
    size_t base = (size_t)b * C_ * T_ + t;
    em[base + 0*T_] = a0;
    em[base + 1*T_] = a1;
    em[base + 2*T_] = a2;
    em[base + 3*T_] = a3;
    em[base + 4*T_] = a4;
    float s0 = a0, s1 = a1, s2 = a2, s3 = a3, s4 = a4;
    #pragma unroll
    for (int off = 1; off < 64; off <<= 1) {
        s0 += __shfl_xor(s0, off, 64);
        s1 += __shfl_xor(s1, off, 64);
        s2 += __shfl_xor(s2, off, 64);
        s3 += __shfl_xor(s3, off, 64);
        s4 += __shfl_xor(s4, off, 64);
    }
    int lane = tid & 63, wv = tid >> 6;
    if (lane == 0) { prd[wv][0]=s0; prd[wv][1]=s1; prd[wv][2]=s2; prd[wv][3]=s3; prd[wv][4]=s4; }
    __syncthreads();
    if (tid < C_) {
        float t4 = (prd[0][tid] + prd[1][tid]) + (prd[2][tid] + prd[3][tid]);
        PA[((half * B_ + b) * NTILE + tile) * C_ + tid] = t4;
    }
}

// ---------------- Kernel B: cum writer (one block per (b,c,tile)) ----------------
__global__ __launch_bounds__(64) void cumwrite_kernel(
    const float* __restrict__ emitA, const float* __restrict__ emitB,
    const float* __restrict__ PA, float* __restrict__ cum)
{
    int bx = blockIdx.x;
    int tile = bx & (NTILE - 1);
    int bc = bx >> 5;
    int b = bc / C_, c = bc - b * C_;
    int lane = threadIdx.x;
    float v = 0.0f;
    if (lane < NTILE && lane < tile)
        v = PA[((0 * B_ + b) * NTILE + lane) * C_ + c]
          + PA[((1 * B_ + b) * NTILE + lane) * C_ + c];
    #pragma unroll
    for (int o = 32; o; o >>= 1) v += __shfl_xor(v, o, 64);
    const float* eA = emitA + ((size_t)b * C_ + c) * T_;
    const float* eB = emitB + ((size_t)b * C_ + c) * T_;
    float* cb = cum + (size_t)b * (T_ + 1) * C_;
    if (tile == 0 && lane == 0) cb[c] = 0.0f;
    float carry = v;
    #pragma unroll
    for (int i = 0; i < 4; ++i) {
        int idx = tile * 256 + i * 64 + lane;
        float e = eA[idx] + eB[idx];
        float si = e;
        #pragma unroll
        for (int o = 1; o < 64; o <<= 1) {
            float n = __shfl_up(si, o, 64);
            if (lane >= o) si += n;
        }
        cb[(size_t)(idx + 1) * C_ + c] = carry + si;
        carry += __shfl(si, 63, 64);
    }
}

// ---------------- Kernel C: per-chunk 80x80 transfer matrices ----------------
// One thread per basis column: full 5-class x 16-slot ring in registers.
// Zero cross-lane ops in the recurrence.
#define CSTEP(PP, TT)                                                         \
    {                                                                         \
        float gv[C_], giv[C_];                                                \
        _Pragma("unroll")                                                     \
        for (int c = 0; c < C_; ++c) {                                        \
            gv[c]  = g_lds[lc][c][16 + (TT)];                                 \
            giv[c] = gi_lds[lc][c][16 + (TT)];                                \
        }                                                                     \
        _Pragma("unroll")                                                     \
        for (int c = 0; c < C_; ++c) {                                        \
            float d0 = 0.f, d1 = 0.f, d2 = 0.f, d3 = 0.f;                     \
            _Pragma("unroll")                                                 \
            for (int q = 0; q < K_; q += 4) {                                 \
                d0 = fmaf(W[c][q+0], ed[c][(q+0+(PP)) & 15], d0);             \
                d1 = fmaf(W[c][q+1], ed[c][(q+1+(PP)) & 15], d1);             \
                d2 = fmaf(W[c][q+2], ed[c][(q+2+(PP)) & 15], d2);             \
                d3 = fmaf(W[c][q+3], ed[c][(q+3+(PP)) & 15], d3);             \
            }                                                                 \
            P[c]  *= gv[c];                                                   \
            iP[c] *= giv[c];                                                  \
            A[c] = P[c] * ((d0 + d1) + (d2 + d3));                            \
        }                                                                     \
        _Pragma("unroll")                                                     \
        for (int c2 = 0; c2 < C_; ++c2) {                                     \
            float Sn = fmaf(eT[0][c2], A[0], fmaf(eT[1][c2], A[1],            \
                       fmaf(eT[2][c2], A[2], fmaf(eT[3][c2], A[3],            \
                            eT[4][c2] * A[4]))));                             \
            W[c2][15 - (PP)] = Sn * iP[c2];                                   \
        }                                                                     \
    }

#define CRENORM()                                                             \
    {                                                                         \
        float a0 = A[0];                                                      \
        bool ok = (a0 > 1e-30f);                                              \
        float r  = ok ? __builtin_amdgcn_rcpf(a0) : 1.0f;                     \
        float lz = ok ? __logf(a0) : 0.0f;                                    \
        _Pragma("unroll")                                                     \
        for (int c = 0; c < C_; ++c) {                                        \
            float f = P[c] * r;                                               \
            _Pragma("unroll")                                                 \
            for (int q = 0; q < K_; ++q) W[c][q] *= f;                        \
            P[c] = 1.0f; iP[c] = 1.0f;                                        \
        }                                                                     \
        z += lz;                                                              \
    }

#define CTAIL(PP)                                                             \
    if ((PP) < remn) {                                                        \
        CSTEP(PP, tl0 + (PP));                                                \
        if ((PP) == remn - 1) {                                               \
            _Pragma("unroll")                                                 \
            for (int c = 0; c < C_; ++c) Afin[c] = A[c];                      \
        }                                                                     \
    }

__global__ __launch_bounds__(320, 1) void chunk_kernel(
    const float* __restrict__ emitA, const float* __restrict__ emitB,
    const int* __restrict__ lengths, const float* __restrict__ trans,
    const float* __restrict__ dur, __hip_bfloat16* __restrict__ Mout,
    float* __restrict__ Rout, float* __restrict__ ezOut,
    float* __restrict__ Zmx)
{
    __shared__ float g_lds[CPB][C_][WPAD];
    __shared__ float gi_lds[CPB][C_][WPAD];
    __shared__ float I16[CPB][C_][16];
    __shared__ float zsh[CPB][80];
    __shared__ float zmx_sh[CPB];

    int blk = blockIdx.x;
    int b = blk >> 5;              // 32 blocks per batch
    int k0 = (blk & 31) * CPB;
    int len = lengths[b];
    int tid = threadIdx.x;
    int lc  = tid / 80;            // local chunk 0..3
    int col = tid - lc * 80;       // basis column 0..79
    int k = k0 + lc;
    int s = (k * len) >> 7;
    int e = ((k + 1) * len) >> 7;
    int L = e - s;                 // 32..64

    // stage g = exp(emit), gi = exp(-emit) for 4 chunks (window = 16 pre + L)
    for (int i = tid; i < CPB * C_ * WIN; i += 320) {
        int ch = i / (C_ * WIN);
        int r2 = i - ch * (C_ * WIN);
        int cc = r2 / WIN;
        int j  = r2 - cc * WIN;
        int kk = k0 + ch;
        int ss = (kk * len) >> 7, ee = ((kk + 1) * len) >> 7;
        int LL = ee - ss;
        int pos = ss - 16 + j;
        float g = 1.0f, gi = 1.0f;
        if (pos >= 0 && j < 16 + LL) {
            size_t gx = ((size_t)b * C_ + cc) * T_ + pos;
            float ev = emitA[gx] + emitB[gx];
            g = __expf(ev); gi = __expf(-ev);
        }
        g_lds[ch][cc][j]  = g;
        gi_lds[ch][cc][j] = gi;
    }
    __syncthreads();
    // inverse-suffix tables for the M epilogue: I16[ch][c][j] = prod_{i=L-j..L-1} gi
    if (tid < CPB * C_) {
        int ch = tid / C_, cc = tid - (tid / C_) * C_;
        int kk = k0 + ch;
        int ss = (kk * len) >> 7, ee = ((kk + 1) * len) >> 7, LL = ee - ss;
        float run = 1.0f;
        I16[ch][cc][0] = 1.0f;
        for (int j = 1; j < 16; ++j) {
            run *= gi_lds[ch][cc][16 + LL - j];
            I16[ch][cc][j] = run;
        }
    }
    __syncthreads();

    // per-thread constants
    float ed[C_][K_], eT[C_][C_];
    #pragma unroll
    for (int c = 0; c < C_; ++c)
        #pragma unroll
        for (int j = 0; j < K_; ++j) ed[c][j] = __expf(dur[c * K_ + j]);
    #pragma unroll
    for (int c = 0; c < C_; ++c)
        #pragma unroll
        for (int c2 = 0; c2 < C_; ++c2) eT[c][c2] = __expf(trans[c * C_ + c2]);

    // ring seed: basis column (j0, c0)
    int j0 = col / C_, c0 = col - j0 * C_;
    float seed = 1.0f;
    for (int j = 16 - j0; j < 16; ++j) seed *= g_lds[lc][c0][j];
    float W[C_][K_];
    #pragma unroll
    for (int c = 0; c < C_; ++c)
        #pragma unroll
        for (int q = 0; q < K_; ++q)
            W[c][q] = (c == c0 && q == j0) ? seed : 0.0f;

    float P[C_], iP[C_], A[C_], Afin[C_];
    #pragma unroll
    for (int c = 0; c < C_; ++c) { P[c] = 1.0f; iP[c] = 1.0f; A[c] = 0.0f; Afin[c] = 0.0f; }
    float z = 0.0f;

    int nfull = (L - 1) >> 4;     // 1..3 (divergent within wave: exec-masked)
    int remn  = L - (nfull << 4); // 1..16
    int tl0 = 0;

    for (int bi = 0; bi < nfull; ++bi) {
        CSTEP(0,  tl0 + 0);  CSTEP(1,  tl0 + 1);  CSTEP(2,  tl0 + 2);  CSTEP(3,  tl0 + 3);
        CSTEP(4,  tl0 + 4);  CSTEP(5,  tl0 + 5);  CSTEP(6,  tl0 + 6);  CSTEP(7,  tl0 + 7);
        CSTEP(8,  tl0 + 8);  CSTEP(9,  tl0 + 9);  CSTEP(10, tl0 + 10); CSTEP(11, tl0 + 11);
        CSTEP(12, tl0 + 12); CSTEP(13, tl0 + 13); CSTEP(14, tl0 + 14); CSTEP(15, tl0 + 15);
        CRENORM();
        tl0 += 16;
    }
    CTAIL(0);  CTAIL(1);  CTAIL(2);  CTAIL(3);
    CTAIL(4);  CTAIL(5);  CTAIL(6);  CTAIL(7);
    CTAIL(8);  CTAIL(9);  CTAIL(10); CTAIL(11);
    CTAIL(12); CTAIL(13); CTAIL(14); CTAIL(15);

    // epilogue: per-chunk zmax, then ez / R / M stores
    zsh[lc][col] = z;
    __syncthreads();
    if (tid < CPB) {
        float m = -3.0e38f;
        for (int i = 0; i < 80; ++i) m = fmaxf(m, zsh[tid][i]);
        zmx_sh[tid] = m;
    }
    __syncthreads();
    float zm = zmx_sh[lc];
    size_t cid = (size_t)b * NC_ + k;
    ezOut[cid * 80 + col] = __expf(z - zm);
    if (col == 0) Zmx[cid] = zm;
    if (k == NC_ - 1) {            // only the last chunk's R is consumed
        #pragma unroll
        for (int c = 0; c < C_; ++c) Rout[(size_t)b * 400 + col * C_ + c] = Afin[c];
    } else {
        __hip_bfloat16* mb = Mout + cid * 6400 + (size_t)col * 80;
        int pn = L & 15;
        #pragma unroll
        for (int slot = 0; slot < K_; ++slot) {
            int j = (slot + pn) & 15;
            #pragma unroll
            for (int c = 0; c < C_; ++c)
                mb[j * C_ + c] = __float2bfloat16(W[c][slot] * P[c] * I16[lc][c][j]);
        }
    }
}

// ---------------- Kernel D: forward/backward vector chains (LDS dbuf, renorm every iter) ----------------
__global__ __launch_bounds__(320) void chain_kernel(
    const __hip_bfloat16* __restrict__ Mst, const float* __restrict__ ezZ,
    const float* __restrict__ Zmx, const float* __restrict__ Rst,
    const float* __restrict__ startv, float* __restrict__ Uvec,
    float* __restrict__ Xvec, float* __restrict__ Zu, float* __restrict__ Zx)
{
    __shared__ float Ml[2][80 * 82];
    __shared__ float vin[80], sv[80], part[4][80];
    __shared__ float red;
    int b = blockIdx.x >> 1;
    int dir = blockIdx.x & 1;
    int tid = threadIdx.x;
    float Z = 0.0f;
    int nmat = (dir == 0) ? NFW : (NC_ - 1 - NFW);   // 63 fwd, 64 bwd

    if (dir == 0) {
        if (tid < 80) vin[tid] = (tid < C_) ? __expf(startv[tid]) : 0.0f;
        __syncthreads();
    } else {
        size_t last = (size_t)b * NC_ + NC_ - 1;
        if (tid < 80) {
            const float* R = Rst + (size_t)b * 400 + (size_t)tid * C_;
            float rs = ((R[0] + R[1]) + (R[2] + R[3])) + R[4];
            sv[tid] = rs * ezZ[last * 80 + tid];
        }
        __syncthreads();
        if (tid < 64) {
            float m = sv[tid];
            if (tid < 16) m = fmaxf(m, sv[tid + 64]);
            #pragma unroll
            for (int o = 32; o; o >>= 1) m = fmaxf(m, __shfl_xor(m, o, 64));
            if (tid == 0) red = m;
        }
        __syncthreads();
        float rm = red;
        if (tid < 80) vin[tid] = sv[tid] / rm;
        Z = Zmx[b * NC_ + NC_ - 1] + __logf(rm);
        __syncthreads();
    }

    // stage first matrix
    int mk0 = (dir == 0) ? 0 : NC_ - 2;
    {
        const unsigned int* mg = (const unsigned int*)(Mst + (size_t)(b * NC_ + mk0) * 6400);
        #pragma unroll
        for (int i = 0; i < 10; ++i) {
            unsigned int u = mg[tid + 320 * i];
            int idx = (tid + 320 * i) * 2;
            int r = idx / 80, c = idx - r * 80;
            Ml[0][r * 82 + c]     = bf16lo(u);
            Ml[0][r * 82 + c + 1] = bf16hi(u);
        }
    }
    __syncthreads();

    int cur = 0;
    int grp = tid / 80, r = tid - grp * 80;
    for (int it = 0; it < nmat; ++it) {
        int k  = (dir == 0) ? it : (NC_ - 2 - it);
        int kn = (dir == 0) ? k + 1 : k - 1;
        bool more = (it + 1 < nmat);
        size_t cid = (size_t)b * NC_ + k;

        unsigned int mu[10];
        if (more) {
            const unsigned int* mg = (const unsigned int*)(Mst + ((size_t)b * NC_ + kn) * 6400);
            #pragma unroll
            for (int i = 0; i < 10; ++i) mu[i] = mg[tid + 320 * i];
        }
        float ezv = 0.0f;
        if (tid < 80) {
            ezv = ezZ[cid * 80 + tid];
            sv[tid] = (dir == 0) ? vin[tid] * ezv : vin[tid];
        }
        __syncthreads();

        float p = 0.0f;
        if (dir == 0) {
            int q0 = grp * 20;
            #pragma unroll
            for (int i = 0; i < 20; ++i)
                p = fmaf(Ml[cur][(q0 + i) * 82 + r], sv[q0 + i], p);
        } else {
            int rowb = grp * 20;
            #pragma unroll
            for (int i = 0; i < 20; ++i)
                p = fmaf(Ml[cur][r * 82 + rowb + i], sv[rowb + i], p);
        }
        part[grp][r] = p;
        if (more) {
            #pragma unroll
            for (int i = 0; i < 10; ++i) {
                unsigned int u = mu[i];
                int idx = (tid + 320 * i) * 2;
                int rr = idx / 80, cc = idx - rr * 80;
                Ml[cur ^ 1][rr * 82 + cc]     = bf16lo(u);
                Ml[cur ^ 1][rr * 82 + cc + 1] = bf16hi(u);
            }
        }
        __syncthreads();

        Z += Zmx[cid];
        if (tid < 80) {
            float nv = (part[0][tid] + part[1][tid]) + (part[2][tid] + part[3][tid]);
            if (dir == 1) nv *= ezv;
            sv[tid] = nv;
        }
        __syncthreads();
        if (tid < 64) {
            float m = sv[tid];
            if (tid < 16) m = fmaxf(m, sv[tid + 64]);
            #pragma unroll
            for (int o = 32; o; o >>= 1) m = fmaxf(m, __shfl_xor(m, o, 64));
            if (tid == 0) red = m;
        }
        __syncthreads();
        float rm = red;
        if (tid < 80) vin[tid] = sv[tid] / rm;
        Z += __logf(rm);
        cur ^= 1;
    }

    if (dir == 0) {
        if (tid < 80) Xvec[b * 80 + tid] = vin[tid];
        if (tid == 0) Zx[b] = Z;
    } else {
        if (tid < 80) Uvec[b * 80 + tid] = vin[tid];
        if (tid == 0) Zu[b] = Z;
    }
}

// ---------------- Kernel E: meet -> partition ----------------
__global__ __launch_bounds__(512) void meet_kernel(
    const float* __restrict__ Uvec, const float* __restrict__ Xvec,
    const float* __restrict__ Zu, const float* __restrict__ Zx,
    float* __restrict__ partition)
{
    int tid = threadIdx.x;
    int b = tid >> 6, lane = tid & 63;
    float v = Uvec[b * 80 + lane] * Xvec[b * 80 + lane];
    if (lane < 16) v += Uvec[b * 80 + 64 + lane] * Xvec[b * 80 + 64 + lane];
    #pragma unroll
    for (int off = 32; off; off >>= 1) v += __shfl_xor(v, off, 64);
    if (lane == 0) partition[b] = Zu[b] + Zx[b] + __logf(v);
}

extern "C" void kernel_launch(void* const* d_in, const int* in_sizes, int n_in,
                              void* d_out, int out_size, void* d_ws, size_t ws_size,
                              hipStream_t stream) {
    (void)in_sizes; (void)n_in; (void)out_size; (void)ws_size;
    const float* seq    = (const float*)d_in[0];
    const int*   lens   = (const int*)  d_in[1];
    const float* W_enc  = (const float*)d_in[2];
    const float* b_enc  = (const float*)d_in[3];
    const float* W_proj = (const float*)d_in[4];
    const float* b_proj = (const float*)d_in[5];
    const float* trans  = (const float*)d_in[6];
    const float* startv = (const float*)d_in[7];
    const float* dur    = (const float*)d_in[8];

    float* out       = (float*)d_out;
    float* partition = out;
    float* cum       = out + B_;

    float* emitA = (float*)d_ws;                              // B*C*T f32
    float* emitB = emitA + (size_t)B_ * C_ * T_;              // B*C*T f32
    __hip_bfloat16* Mst = (__hip_bfloat16*)(emitB + (size_t)B_ * C_ * T_);  // B*NC*6400 bf16
    float* Rst = (float*)(Mst + (size_t)B_ * NC_ * 6400);     // B*400 f32 (last chunk only)
    float* ezS = Rst + (size_t)B_ * 400;                      // B*NC*80 f32
    float* Zmx = ezS + (size_t)B_ * NC_ * 80;                 // B*NC f32
    float* PA  = Zmx + (size_t)B_ * NC_;                      // 2*B*NTILE*C f32
    float* Uv  = PA  + 2 * B_ * NTILE * C_;                   // B*80
    float* Xv  = Uv  + B_ * 80;                               // B*80
    float* Zu  = Xv  + B_ * 80;                               // B
    float* Zx  = Zu  + B_;                                    // B

    encoder_kernel<<<512, 256, 0, stream>>>(seq, W_enc, b_enc, W_proj, b_proj, emitA, emitB, PA);
    chunk_kernel<<<B_ * NC_ / CPB, 320, 0, stream>>>(emitA, emitB, lens, trans, dur, Mst, Rst, ezS, Zmx);
    cumwrite_kernel<<<B_ * C_ * NTILE, 64, 0, stream>>>(emitA, emitB, PA, cum);
    chain_kernel<<<16, 320, 0, stream>>>(Mst, ezS, Zmx, Rst, startv, Uv, Xv, Zu, Zx);
    meet_kernel<<<1, 512, 0, stream>>>(Uv, Xv, Zu, Zx, partition);
}

// Round 9
// 192.439 us; speedup vs baseline: 2.3702x; 2.3702x over previous
//
#include <hip/hip_runtime.h>
#include <hip/hip_bf16.h>

#define B_ 8
#define T_ 8192
#define HID_ 256
#define C_ 5
#define K_ 16
#define NC_ 128   // chunks per batch
#define CPB 4     // chunks per block (chunk_kernel)
#define NTILE 32  // 256-position tiles per batch (cumsum pipeline)
#define WIN 80    // 16 pre-window + LMAX(64)
#define WPAD 84
#define NFW 63    // forward-chain matrices k=0..62; backward: R(127), 126..63

__device__ __forceinline__ float gelu_tanh(float x) {
    float u = 0.7978845608028654f * (x + 0.044715f * x * x * x);
    float e = __expf(2.0f * u);
    float th = 1.0f - 2.0f / (e + 1.0f);
    return 0.5f * x * (1.0f + th);
}

__device__ __forceinline__ float bf16lo(unsigned int u) {
    return __uint_as_float(u << 16);
}
__device__ __forceinline__ float bf16hi(unsigned int u) {
    return __uint_as_float(u & 0xffff0000u);
}
// force a block-uniform value into an SGPR
__device__ __forceinline__ float sgpr_uniform(float x) {
    return __uint_as_float(__builtin_amdgcn_readfirstlane(__float_as_uint(x)));
}

// ---------------- Kernel A: encoder (hidden split) -> emitA/emitB + per-tile class sums ----------------
__global__ __launch_bounds__(256) void encoder_kernel(
    const float* __restrict__ seq, const float* __restrict__ W_enc,
    const float* __restrict__ b_enc, const float* __restrict__ W_proj,
    const float* __restrict__ b_proj, float* __restrict__ emitA,
    float* __restrict__ emitB, float* __restrict__ PA)
{
    __shared__ float4 we[128];
    __shared__ float  be[128];
    __shared__ float  wp[128 * C_];
    __shared__ float  prd[4][C_];
    int tid = threadIdx.x;
    int half = blockIdx.x >> 8;
    int blk  = blockIdx.x & 255;
    int h0 = half * 128;
    if (tid < 128) {
        int h = h0 + tid;
        we[tid] = make_float4(W_enc[0*HID_+h], W_enc[1*HID_+h], W_enc[2*HID_+h], W_enc[3*HID_+h]);
        be[tid] = b_enc[h];
    }
    for (int i = tid; i < 128 * C_; i += 256) wp[i] = W_proj[h0 * C_ + i];
    __syncthreads();
    int b = blk >> 5;
    int tile = blk & 31;
    int t = tile * 256 + tid;
    float4 s = reinterpret_cast<const float4*>(seq)[(size_t)b * T_ + t];
    float a0, a1, a2, a3, a4;
    if (half == 0) { a0 = b_proj[0]; a1 = b_proj[1]; a2 = b_proj[2]; a3 = b_proj[3]; a4 = b_proj[4]; }
    else           { a0 = a1 = a2 = a3 = a4 = 0.0f; }
    #pragma unroll 8
    for (int h = 0; h < 128; ++h) {
        float4 w = we[h];
        float pre = be[h] + s.x*w.x + s.y*w.y + s.z*w.z + s.w*w.w;
        float hd = gelu_tanh(pre);
        a0 = fmaf(hd, wp[h*C_+0], a0);
        a1 = fmaf(hd, wp[h*C_+1], a1);
        a2 = fmaf(hd, wp[h*C_+2], a2);
        a3 = fmaf(hd, wp[h*C_+3], a3);
        a4 = fmaf(hd, wp[h*C_+4], a4);
    }
    float* em = half ? emitB : emitA;
    size_t base = (size_t)b * C_ * T_ + t;
    em[base + 0*T_] = a0;
    em[base + 1*T_] = a1;
    em[base + 2*T_] = a2;
    em[base + 3*T_] = a3;
    em[base + 4*T_] = a4;
    float s0 = a0, s1 = a1, s2 = a2, s3 = a3, s4 = a4;
    #pragma unroll
    for (int off = 1; off < 64; off <<= 1) {
        s0 += __shfl_xor(s0, off, 64);
        s1 += __shfl_xor(s1, off, 64);
        s2 += __shfl_xor(s2, off, 64);
        s3 += __shfl_xor(s3, off, 64);
        s4 += __shfl_xor(s4, off, 64);
    }
    int lane = tid & 63, wv = tid >> 6;
    if (lane == 0) { prd[wv][0]=s0; prd[wv][1]=s1; prd[wv][2]=s2; prd[wv][3]=s3; prd[wv][4]=s4; }
    __syncthreads();
    if (tid < C_) {
        float t4 = (prd[0][tid] + prd[1][tid]) + (prd[2][tid] + prd[3][tid]);
        PA[((half * B_ + b) * NTILE + tile) * C_ + tid] = t4;
    }
}

// ---------------- Kernel B: cum writer (one block per (b,c,tile)) ----------------
__global__ __launch_bounds__(64) void cumwrite_kernel(
    const float* __restrict__ emitA, const float* __restrict__ emitB,
    const float* __restrict__ PA, float* __restrict__ cum)
{
    int bx = blockIdx.x;
    int tile = bx & (NTILE - 1);
    int bc = bx >> 5;
    int b = bc / C_, c = bc - b * C_;
    int lane = threadIdx.x;
    float v = 0.0f;
    if (lane < NTILE && lane < tile)
        v = PA[((0 * B_ + b) * NTILE + lane) * C_ + c]
          + PA[((1 * B_ + b) * NTILE + lane) * C_ + c];
    #pragma unroll
    for (int o = 32; o; o >>= 1) v += __shfl_xor(v, o, 64);
    const float* eA = emitA + ((size_t)b * C_ + c) * T_;
    const float* eB = emitB + ((size_t)b * C_ + c) * T_;
    float* cb = cum + (size_t)b * (T_ + 1) * C_;
    if (tile == 0 && lane == 0) cb[c] = 0.0f;
    float carry = v;
    #pragma unroll
    for (int i = 0; i < 4; ++i) {
        int idx = tile * 256 + i * 64 + lane;
        float e = eA[idx] + eB[idx];
        float si = e;
        #pragma unroll
        for (int o = 1; o < 64; o <<= 1) {
            float n = __shfl_up(si, o, 64);
            if (lane >= o) si += n;
        }
        cb[(size_t)(idx + 1) * C_ + c] = carry + si;
        carry += __shfl(si, 63, 64);
    }
}

// ---------------- Kernel C: per-chunk 80x80 transfer matrices ----------------
// One thread per basis column: full 5-class x 16-slot ring in registers.
// ed table in SGPRs (block-uniform, readfirstlane); zero cross-lane ops.
#define CSTEP(PP, TT)                                                         \
    {                                                                         \
        float gv[C_], iv[C_];                                                 \
        _Pragma("unroll")                                                     \
        for (int c = 0; c < C_; ++c) gv[c] = g_lds[lc][c][16 + (TT)];         \
        _Pragma("unroll")                                                     \
        for (int c = 0; c < C_; ++c) {                                        \
            float d0 = 0.f, d1 = 0.f, d2 = 0.f, d3 = 0.f;                     \
            _Pragma("unroll")                                                 \
            for (int q = 0; q < K_; q += 4) {                                 \
                d0 = fmaf(W[c][q+0], eds[c*K_ + ((q+0+(PP)) & 15)], d0);      \
                d1 = fmaf(W[c][q+1], eds[c*K_ + ((q+1+(PP)) & 15)], d1);      \
                d2 = fmaf(W[c][q+2], eds[c*K_ + ((q+2+(PP)) & 15)], d2);      \
                d3 = fmaf(W[c][q+3], eds[c*K_ + ((q+3+(PP)) & 15)], d3);      \
            }                                                                 \
            P[c] *= gv[c];                                                    \
            iv[c] = __builtin_amdgcn_rcpf(P[c]);                              \
            A[c] = P[c] * ((d0 + d1) + (d2 + d3));                            \
        }                                                                     \
        _Pragma("unroll")                                                     \
        for (int c2 = 0; c2 < C_; ++c2) {                                     \
            float Sn = fmaf(eT[0][c2], A[0], fmaf(eT[1][c2], A[1],            \
                       fmaf(eT[2][c2], A[2], fmaf(eT[3][c2], A[3],            \
                            eT[4][c2] * A[4]))));                             \
            W[c2][15 - (PP)] = Sn * iv[c2];                                   \
        }                                                                     \
    }

#define CRENORM()                                                             \
    {                                                                         \
        float a0 = A[0];                                                      \
        bool ok = (a0 > 1e-30f);                                              \
        float r  = ok ? __builtin_amdgcn_rcpf(a0) : 1.0f;                     \
        float lz = ok ? __logf(a0) : 0.0f;                                    \
        _Pragma("unroll")                                                     \
        for (int c = 0; c < C_; ++c) {                                        \
            float f = P[c] * r;                                               \
            _Pragma("unroll")                                                 \
            for (int q = 0; q < K_; ++q) W[c][q] *= f;                        \
            P[c] = 1.0f;                                                      \
        }                                                                     \
        z += lz;                                                              \
    }

#define CTAIL(PP)                                                             \
    if ((PP) < remn) { CSTEP(PP, tl0 + (PP)); }

__global__
__attribute__((amdgpu_flat_work_group_size(320, 320)))
__attribute__((amdgpu_waves_per_eu(1, 2)))
void chunk_kernel(
    const float* __restrict__ emitA, const float* __restrict__ emitB,
    const int* __restrict__ lengths, const float* __restrict__ trans,
    const float* __restrict__ dur, __hip_bfloat16* __restrict__ Mout,
    float* __restrict__ Rout, float* __restrict__ ezOut,
    float* __restrict__ Zmx)
{
    __shared__ float g_lds[CPB][C_][WPAD];
    __shared__ float I16[CPB][C_][16];
    __shared__ float zsh[CPB][80];
    __shared__ float zmx_sh[CPB];

    int blk = blockIdx.x;
    int b = blk >> 5;              // 32 blocks per batch
    int k0 = (blk & 31) * CPB;
    int len = lengths[b];
    int tid = threadIdx.x;
    int lc  = tid / 80;            // local chunk 0..3
    int col = tid - lc * 80;       // basis column 0..79
    int k = k0 + lc;
    int s = (k * len) >> 7;
    int e = ((k + 1) * len) >> 7;
    int L = e - s;                 // 32..64

    // stage g = exp(emit) for 4 chunks (window = 16 pre + L)
    for (int i = tid; i < CPB * C_ * WIN; i += 320) {
        int ch = i / (C_ * WIN);
        int r2 = i - ch * (C_ * WIN);
        int cc = r2 / WIN;
        int j  = r2 - cc * WIN;
        int kk = k0 + ch;
        int ss = (kk * len) >> 7, ee = ((kk + 1) * len) >> 7;
        int LL = ee - ss;
        int pos = ss - 16 + j;
        float g = 1.0f;
        if (pos >= 0 && j < 16 + LL) {
            size_t gx = ((size_t)b * C_ + cc) * T_ + pos;
            g = __expf(emitA[gx] + emitB[gx]);
        }
        g_lds[ch][cc][j] = g;
    }
    __syncthreads();
    // inverse-suffix tables: I16[ch][c][j] = prod_{i=L-j..L-1} 1/g  (rcp approx)
    if (tid < CPB * C_) {
        int ch = tid / C_, cc = tid - (tid / C_) * C_;
        int kk = k0 + ch;
        int ss = (kk * len) >> 7, ee = ((kk + 1) * len) >> 7, LL = ee - ss;
        float run = 1.0f;
        I16[ch][cc][0] = 1.0f;
        for (int j = 1; j < 16; ++j) {
            run *= __builtin_amdgcn_rcpf(g_lds[ch][cc][16 + LL - j]);
            I16[ch][cc][j] = run;
        }
    }
    __syncthreads();

    // ed table -> SGPRs (block-uniform); eT stays VGPR (25)
    float eds[C_ * K_];
    #pragma unroll
    for (int c = 0; c < C_; ++c)
        #pragma unroll
        for (int j = 0; j < K_; ++j)
            eds[c * K_ + j] = sgpr_uniform(__expf(dur[c * K_ + j]));
    float eT[C_][C_];
    #pragma unroll
    for (int c = 0; c < C_; ++c)
        #pragma unroll
        for (int c2 = 0; c2 < C_; ++c2) eT[c][c2] = __expf(trans[c * C_ + c2]);

    // ring seed: basis column (j0, c0)
    int j0 = col / C_, c0 = col - j0 * C_;
    float seed = 1.0f;
    for (int j = 16 - j0; j < 16; ++j) seed *= g_lds[lc][c0][j];
    float W[C_][K_];
    #pragma unroll
    for (int c = 0; c < C_; ++c)
        #pragma unroll
        for (int q = 0; q < K_; ++q)
            W[c][q] = (c == c0 && q == j0) ? seed : 0.0f;

    float P[C_], A[C_];
    #pragma unroll
    for (int c = 0; c < C_; ++c) { P[c] = 1.0f; A[c] = 0.0f; }
    float z = 0.0f;

    int nfull = (L - 1) >> 4;     // 1..3 (divergent within wave: exec-masked)
    int remn  = L - (nfull << 4); // 1..16
    int tl0 = 0;

    for (int bi = 0; bi < nfull; ++bi) {
        CSTEP(0,  tl0 + 0);  CSTEP(1,  tl0 + 1);  CSTEP(2,  tl0 + 2);  CSTEP(3,  tl0 + 3);
        CSTEP(4,  tl0 + 4);  CSTEP(5,  tl0 + 5);  CSTEP(6,  tl0 + 6);  CSTEP(7,  tl0 + 7);
        CSTEP(8,  tl0 + 8);  CSTEP(9,  tl0 + 9);  CSTEP(10, tl0 + 10); CSTEP(11, tl0 + 11);
        CSTEP(12, tl0 + 12); CSTEP(13, tl0 + 13); CSTEP(14, tl0 + 14); CSTEP(15, tl0 + 15);
        CRENORM();
        tl0 += 16;
    }
    CTAIL(0);  CTAIL(1);  CTAIL(2);  CTAIL(3);
    CTAIL(4);  CTAIL(5);  CTAIL(6);  CTAIL(7);
    CTAIL(8);  CTAIL(9);  CTAIL(10); CTAIL(11);
    CTAIL(12); CTAIL(13); CTAIL(14); CTAIL(15);
    // after the tail, A[] holds the final-step alpha contribution of this column

    // epilogue: per-chunk zmax, then ez / R / M stores
    zsh[lc][col] = z;
    __syncthreads();
    if (tid < CPB) {
        float m = -3.0e38f;
        for (int i = 0; i < 80; ++i) m = fmaxf(m, zsh[tid][i]);
        zmx_sh[tid] = m;
    }
    __syncthreads();
    float zm = zmx_sh[lc];
    size_t cid = (size_t)b * NC_ + k;
    ezOut[cid * 80 + col] = __expf(z - zm);
    if (col == 0) Zmx[cid] = zm;
    if (k == NC_ - 1) {            // only the last chunk's R is consumed
        #pragma unroll
        for (int c = 0; c < C_; ++c) Rout[(size_t)b * 400 + col * C_ + c] = A[c];
    } else {
        __hip_bfloat16* mb = Mout + cid * 6400 + (size_t)col * 80;
        int pn = L & 15;
        #pragma unroll
        for (int slot = 0; slot < K_; ++slot) {
            int j = (slot + pn) & 15;
            #pragma unroll
            for (int c = 0; c < C_; ++c)
                mb[j * C_ + c] = __float2bfloat16(W[c][slot] * P[c] * I16[lc][c][j]);
        }
    }
}

// ---------------- Kernel D: forward/backward vector chains (LDS dbuf, renorm every iter) ----------------
__global__ __launch_bounds__(320) void chain_kernel(
    const __hip_bfloat16* __restrict__ Mst, const float* __restrict__ ezZ,
    const float* __restrict__ Zmx, const float* __restrict__ Rst,
    const float* __restrict__ startv, float* __restrict__ Uvec,
    float* __restrict__ Xvec, float* __restrict__ Zu, float* __restrict__ Zx)
{
    __shared__ float Ml[2][80 * 82];
    __shared__ float vin[80], sv[80], part[4][80];
    __shared__ float red;
    int b = blockIdx.x >> 1;
    int dir = blockIdx.x & 1;
    int tid = threadIdx.x;
    float Z = 0.0f;
    int nmat = (dir == 0) ? NFW : (NC_ - 1 - NFW);   // 63 fwd, 64 bwd

    if (dir == 0) {
        if (tid < 80) vin[tid] = (tid < C_) ? __expf(startv[tid]) : 0.0f;
        __syncthreads();
    } else {
        size_t last = (size_t)b * NC_ + NC_ - 1;
        if (tid < 80) {
            const float* R = Rst + (size_t)b * 400 + (size_t)tid * C_;
            float rs = ((R[0] + R[1]) + (R[2] + R[3])) + R[4];
            sv[tid] = rs * ezZ[last * 80 + tid];
        }
        __syncthreads();
        if (tid < 64) {
            float m = sv[tid];
            if (tid < 16) m = fmaxf(m, sv[tid + 64]);
            #pragma unroll
            for (int o = 32; o; o >>= 1) m = fmaxf(m, __shfl_xor(m, o, 64));
            if (tid == 0) red = m;
        }
        __syncthreads();
        float rm = red;
        if (tid < 80) vin[tid] = sv[tid] / rm;
        Z = Zmx[b * NC_ + NC_ - 1] + __logf(rm);
        __syncthreads();
    }

    // stage first matrix
    int mk0 = (dir == 0) ? 0 : NC_ - 2;
    {
        const unsigned int* mg = (const unsigned int*)(Mst + (size_t)(b * NC_ + mk0) * 6400);
        #pragma unroll
        for (int i = 0; i < 10; ++i) {
            unsigned int u = mg[tid + 320 * i];
            int idx = (tid + 320 * i) * 2;
            int r = idx / 80, c = idx - r * 80;
            Ml[0][r * 82 + c]     = bf16lo(u);
            Ml[0][r * 82 + c + 1] = bf16hi(u);
        }
    }
    __syncthreads();

    int cur = 0;
    int grp = tid / 80, r = tid - grp * 80;
    for (int it = 0; it < nmat; ++it) {
        int k  = (dir == 0) ? it : (NC_ - 2 - it);
        int kn = (dir == 0) ? k + 1 : k - 1;
        bool more = (it + 1 < nmat);
        size_t cid = (size_t)b * NC_ + k;

        unsigned int mu[10];
        if (more) {
            const unsigned int* mg = (const unsigned int*)(Mst + ((size_t)b * NC_ + kn) * 6400);
            #pragma unroll
            for (int i = 0; i < 10; ++i) mu[i] = mg[tid + 320 * i];
        }
        float ezv = 0.0f;
        if (tid < 80) {
            ezv = ezZ[cid * 80 + tid];
            sv[tid] = (dir == 0) ? vin[tid] * ezv : vin[tid];
        }
        __syncthreads();

        float p = 0.0f;
        if (dir == 0) {
            int q0 = grp * 20;
            #pragma unroll
            for (int i = 0; i < 20; ++i)
                p = fmaf(Ml[cur][(q0 + i) * 82 + r], sv[q0 + i], p);
        } else {
            int rowb = grp * 20;
            #pragma unroll
            for (int i = 0; i < 20; ++i)
                p = fmaf(Ml[cur][r * 82 + rowb + i], sv[rowb + i], p);
        }
        part[grp][r] = p;
        if (more) {
            #pragma unroll
            for (int i = 0; i < 10; ++i) {
                unsigned int u = mu[i];
                int idx = (tid + 320 * i) * 2;
                int rr = idx / 80, cc = idx - rr * 80;
                Ml[cur ^ 1][rr * 82 + cc]     = bf16lo(u);
                Ml[cur ^ 1][rr * 82 + cc + 1] = bf16hi(u);
            }
        }
        __syncthreads();

        Z += Zmx[cid];
        if (tid < 80) {
            float nv = (part[0][tid] + part[1][tid]) + (part[2][tid] + part[3][tid]);
            if (dir == 1) nv *= ezv;
            sv[tid] = nv;
        }
        __syncthreads();
        if (tid < 64) {
            float m = sv[tid];
            if (tid < 16) m = fmaxf(m, sv[tid + 64]);
            #pragma unroll
            for (int o = 32; o; o >>= 1) m = fmaxf(m, __shfl_xor(m, o, 64));
            if (tid == 0) red = m;
        }
        __syncthreads();
        float rm = red;
        if (tid < 80) vin[tid] = sv[tid] / rm;
        Z += __logf(rm);
        cur ^= 1;
    }

    if (dir == 0) {
        if (tid < 80) Xvec[b * 80 + tid] = vin[tid];
        if (tid == 0) Zx[b] = Z;
    } else {
        if (tid < 80) Uvec[b * 80 + tid] = vin[tid];
        if (tid == 0) Zu[b] = Z;
    }
}

// ---------------- Kernel E: meet -> partition ----------------
__global__ __launch_bounds__(512) void meet_kernel(
    const float* __restrict__ Uvec, const float* __restrict__ Xvec,
    const float* __restrict__ Zu, const float* __restrict__ Zx,
    float* __restrict__ partition)
{
    int tid = threadIdx.x;
    int b = tid >> 6, lane = tid & 63;
    float v = Uvec[b * 80 + lane] * Xvec[b * 80 + lane];
    if (lane < 16) v += Uvec[b * 80 + 64 + lane] * Xvec[b * 80 + 64 + lane];
    #pragma unroll
    for (int off = 32; off; off >>= 1) v += __shfl_xor(v, off, 64);
    if (lane == 0) partition[b] = Zu[b] + Zx[b] + __logf(v);
}

extern "C" void kernel_launch(void* const* d_in, const int* in_sizes, int n_in,
                              void* d_out, int out_size, void* d_ws, size_t ws_size,
                              hipStream_t stream) {
    (void)in_sizes; (void)n_in; (void)out_size; (void)ws_size;
    const float* seq    = (const float*)d_in[0];
    const int*   lens   = (const int*)  d_in[1];
    const float* W_enc  = (const float*)d_in[2];
    const float* b_enc  = (const float*)d_in[3];
    const float* W_proj = (const float*)d_in[4];
    const float* b_proj = (const float*)d_in[5];
    const float* trans  = (const float*)d_in[6];
    const float* startv = (const float*)d_in[7];
    const float* dur    = (const float*)d_in[8];

    float* out       = (float*)d_out;
    float* partition = out;
    float* cum       = out + B_;

    float* emitA = (float*)d_ws;                              // B*C*T f32
    float* emitB = emitA + (size_t)B_ * C_ * T_;              // B*C*T f32
    __hip_bfloat16* Mst = (__hip_bfloat16*)(emitB + (size_t)B_ * C_ * T_);  // B*NC*6400 bf16
    float* Rst = (float*)(Mst + (size_t)B_ * NC_ * 6400);     // B*400 f32 (last chunk only)
    float* ezS = Rst + (size_t)B_ * 400;                      // B*NC*80 f32
    float* Zmx = ezS + (size_t)B_ * NC_ * 80;                 // B*NC f32
    float* PA  = Zmx + (size_t)B_ * NC_;                      // 2*B*NTILE*C f32
    float* Uv  = PA  + 2 * B_ * NTILE * C_;                   // B*80
    float* Xv  = Uv  + B_ * 80;                               // B*80
    float* Zu  = Xv  + B_ * 80;                               // B
    float* Zx  = Zu  + B_;                                    // B

    encoder_kernel<<<512, 256, 0, stream>>>(seq, W_enc, b_enc, W_proj, b_proj, emitA, emitB, PA);
    chunk_kernel<<<B_ * NC_ / CPB, 320, 0, stream>>>(emitA, emitB, lens, trans, dur, Mst, Rst, ezS, Zmx);
    cumwrite_kernel<<<B_ * C_ * NTILE, 64, 0, stream>>>(emitA, emitB, PA, cum);
    chain_kernel<<<16, 320, 0, stream>>>(Mst, ezS, Zmx, Rst, startv, Uv, Xv, Zu, Zx);
    meet_kernel<<<1, 512, 0, stream>>>(Uv, Xv, Zu, Zx, partition);
}

// Round 10
// 91.343 us; speedup vs baseline: 4.9934x; 2.1068x over previous
//
#include <hip/hip_runtime.h>
#include <hip/hip_bf16.h>

#define B_ 8
#define T_ 8192
#define HID_ 256
#define C_ 5
#define K_ 16
#define NC_ 32    // chunks per batch
#define NTILE 32  // 256-position tiles per batch (cumsum pipeline)
#define GSPAN 272 // 16 pre-window + LMAX(256)
#define NFW 15    // forward-chain matrices k=0..14; backward: R(31), M30..M15

__device__ __forceinline__ float gelu_tanh(float x) {
    float u = 0.7978845608028654f * (x + 0.044715f * x * x * x);
    float e = __expf(2.0f * u);
    float th = 1.0f - 2.0f / (e + 1.0f);
    return 0.5f * x * (1.0f + th);
}

__device__ __forceinline__ float bf16lo(unsigned int u) {
    return __uint_as_float(u << 16);
}
__device__ __forceinline__ float bf16hi(unsigned int u) {
    return __uint_as_float(u & 0xffff0000u);
}

// ---------------- Kernel A: encoder (hidden split) -> emitA/emitB + per-tile class sums ----------------
__global__ __launch_bounds__(256) void encoder_kernel(
    const float* __restrict__ seq, const float* __restrict__ W_enc,
    const float* __restrict__ b_enc, const float* __restrict__ W_proj,
    const float* __restrict__ b_proj, float* __restrict__ emitA,
    float* __restrict__ emitB, float* __restrict__ PA)
{
    __shared__ float4 we[128];
    __shared__ float  be[128];
    __shared__ float  wp[128 * C_];
    __shared__ float  prd[4][C_];
    int tid = threadIdx.x;
    int half = blockIdx.x >> 8;
    int blk  = blockIdx.x & 255;
    int h0 = half * 128;
    if (tid < 128) {
        int h = h0 + tid;
        we[tid] = make_float4(W_enc[0*HID_+h], W_enc[1*HID_+h], W_enc[2*HID_+h], W_enc[3*HID_+h]);
        be[tid] = b_enc[h];
    }
    for (int i = tid; i < 128 * C_; i += 256) wp[i] = W_proj[h0 * C_ + i];
    __syncthreads();
    int b = blk >> 5;
    int tile = blk & 31;
    int t = tile * 256 + tid;
    float4 s = reinterpret_cast<const float4*>(seq)[(size_t)b * T_ + t];
    float a0, a1, a2, a3, a4;
    if (half == 0) { a0 = b_proj[0]; a1 = b_proj[1]; a2 = b_proj[2]; a3 = b_proj[3]; a4 = b_proj[4]; }
    else           { a0 = a1 = a2 = a3 = a4 = 0.0f; }
    #pragma unroll 8
    for (int h = 0; h < 128; ++h) {
        float4 w = we[h];
        float pre = be[h] + s.x*w.x + s.y*w.y + s.z*w.z + s.w*w.w;
        float hd = gelu_tanh(pre);
        a0 = fmaf(hd, wp[h*C_+0], a0);
        a1 = fmaf(hd, wp[h*C_+1], a1);
        a2 = fmaf(hd, wp[h*C_+2], a2);
        a3 = fmaf(hd, wp[h*C_+3], a3);
        a4 = fmaf(hd, wp[h*C_+4], a4);
    }
    float* em = half ? emitB : emitA;
    size_t base = (size_t)b * C_ * T_ + t;
    em[base + 0*T_] = a0;
    em[base + 1*T_] = a1;
    em[base + 2*T_] = a2;
    em[base + 3*T_] = a3;
    em[base + 4*T_] = a4;
    float s0 = a0, s1 = a1, s2 = a2, s3 = a3, s4 = a4;
    #pragma unroll
    for (int off = 1; off < 64; off <<= 1) {
        s0 += __shfl_xor(s0, off, 64);
        s1 += __shfl_xor(s1, off, 64);
        s2 += __shfl_xor(s2, off, 64);
        s3 += __shfl_xor(s3, off, 64);
        s4 += __shfl_xor(s4, off, 64);
    }
    int lane = tid & 63, wv = tid >> 6;
    if (lane == 0) { prd[wv][0]=s0; prd[wv][1]=s1; prd[wv][2]=s2; prd[wv][3]=s3; prd[wv][4]=s4; }
    __syncthreads();
    if (tid < C_) {
        float t4 = (prd[0][tid] + prd[1][tid]) + (prd[2][tid] + prd[3][tid]);
        PA[((half * B_ + b) * NTILE + tile) * C_ + tid] = t4;
    }
}

// ---------------- Kernel B: cum writer (one block per (b,c,tile)) ----------------
__global__ __launch_bounds__(64) void cumwrite_kernel(
    const float* __restrict__ emitA, const float* __restrict__ emitB,
    const float* __restrict__ PA, float* __restrict__ cum)
{
    int bx = blockIdx.x;
    int tile = bx & (NTILE - 1);
    int bc = bx >> 5;
    int b = bc / C_, c = bc - b * C_;
    int lane = threadIdx.x;
    float v = 0.0f;
    if (lane < NTILE && lane < tile)
        v = PA[((0 * B_ + b) * NTILE + lane) * C_ + c]
          + PA[((1 * B_ + b) * NTILE + lane) * C_ + c];
    #pragma unroll
    for (int o = 32; o; o >>= 1) v += __shfl_xor(v, o, 64);
    const float* eA = emitA + ((size_t)b * C_ + c) * T_;
    const float* eB = emitB + ((size_t)b * C_ + c) * T_;
    float* cb = cum + (size_t)b * (T_ + 1) * C_;
    if (tile == 0 && lane == 0) cb[c] = 0.0f;
    float carry = v;
    #pragma unroll
    for (int i = 0; i < 4; ++i) {
        int idx = tile * 256 + i * 64 + lane;
        float e = eA[idx] + eB[idx];
        float si = e;
        #pragma unroll
        for (int o = 1; o < 64; o <<= 1) {
            float n = __shfl_up(si, o, 64);
            if (lane >= o) si += n;
        }
        cb[(size_t)(idx + 1) * C_ + c] = carry + si;
        carry += __shfl(si, 63, 64);
    }
}

// ---------------- Kernel C: per-chunk 80x80 transfer matrices (r4 shuffle design) ----------------
#define CHUNK_STEP(PP, TL)                                                    \
    {                                                                         \
        float g  = g_lds[c][16 + (TL)];                                       \
        float gi = gi_lds[c][16 + (TL)];                                      \
        P *= g; invP *= gi;                                                   \
        float d0 = 0.f, d1 = 0.f, d2 = 0.f, d3 = 0.f;                         \
        d0 = fmaf(W[0],  ed[(0  + (PP)) & 15], d0);                           \
        d1 = fmaf(W[1],  ed[(1  + (PP)) & 15], d1);                           \
        d2 = fmaf(W[2],  ed[(2  + (PP)) & 15], d2);                           \
        d3 = fmaf(W[3],  ed[(3  + (PP)) & 15], d3);                           \
        d0 = fmaf(W[4],  ed[(4  + (PP)) & 15], d0);                           \
        d1 = fmaf(W[5],  ed[(5  + (PP)) & 15], d1);                           \
        d2 = fmaf(W[6],  ed[(6  + (PP)) & 15], d2);                           \
        d3 = fmaf(W[7],  ed[(7  + (PP)) & 15], d3);                           \
        d0 = fmaf(W[8],  ed[(8  + (PP)) & 15], d0);                           \
        d1 = fmaf(W[9],  ed[(9  + (PP)) & 15], d1);                           \
        d2 = fmaf(W[10], ed[(10 + (PP)) & 15], d2);                           \
        d3 = fmaf(W[11], ed[(11 + (PP)) & 15], d3);                           \
        d0 = fmaf(W[12], ed[(12 + (PP)) & 15], d0);                           \
        d1 = fmaf(W[13], ed[(13 + (PP)) & 15], d1);                           \
        d2 = fmaf(W[14], ed[(14 + (PP)) & 15], d2);                           \
        d3 = fmaf(W[15], ed[(15 + (PP)) & 15], d3);                           \
        float dotv = (d0 + d1) + (d2 + d3);                                   \
        astep = P * dotv;                                                     \
        float A0 = __shfl(astep, base5 + 0, 64);                              \
        float A1 = __shfl(astep, base5 + 1, 64);                              \
        float A2 = __shfl(astep, base5 + 2, 64);                              \
        float A3 = __shfl(astep, base5 + 3, 64);                              \
        float A4 = __shfl(astep, base5 + 4, 64);                              \
        A0v = A0;                                                             \
        float Sn = fmaf(eT[0], A0, fmaf(eT[1], A1, fmaf(eT[2], A2,           \
                   fmaf(eT[3], A3, eT[4] * A4))));                            \
        W[15 - (PP)] = Sn * invP;                                             \
    }

#define CHUNK_RENORM()                                                        \
    {                                                                         \
        bool ok = (A0v > 1e-30f);                                             \
        float r  = ok ? __builtin_amdgcn_rcpf(A0v) : 1.0f;                    \
        float lz = ok ? __logf(A0v) : 0.0f;                                   \
        float f = P * r;                                                      \
        _Pragma("unroll") for (int q = 0; q < 16; ++q) W[q] *= f;             \
        P = 1.0f; invP = 1.0f; z += lz;                                       \
    }

#define TAIL_STEP(PP)                                                         \
    if ((PP) < rem) {                                                         \
        CHUNK_STEP(PP, tl0 + (PP));                                           \
        if ((PP) == rem - 1) Afin = astep;                                    \
        if ((((PP) & 7) == 7) && ((PP) < rem - 1)) CHUNK_RENORM();            \
    }

__global__ __launch_bounds__(448) void chunk_kernel(
    const float* __restrict__ emitA, const float* __restrict__ emitB,
    const int* __restrict__ lengths, const float* __restrict__ trans,
    const float* __restrict__ dur, __hip_bfloat16* __restrict__ Mout,
    float* __restrict__ Rout, float* __restrict__ ezOut,
    float* __restrict__ Zmx)
{
    __shared__ float g_lds[C_][GSPAN + 4];
    __shared__ float gi_lds[C_][GSPAN + 4];
    __shared__ float zsh[80];
    __shared__ float zred;
    int blk = blockIdx.x;
    int b = blk >> 5, k = blk & (NC_ - 1);
    int len = lengths[b];
    int s = (k * len) >> 5;
    int e = ((k + 1) * len) >> 5;
    int L = e - s;                       // 128..256
    int tid = threadIdx.x;

    // stage g = exp(emit), gi = exp(-emit); window = 16-pre + L
    for (int i = tid; i < C_ * GSPAN; i += 448) {
        int cc = i / GSPAN, j = i - cc * GSPAN;
        int pos = s - 16 + j;
        float g = 1.0f, gi = 1.0f;
        if (pos >= 0 && j < 16 + L) {
            size_t gx = ((size_t)b * C_ + cc) * T_ + pos;
            float ev = emitA[gx] + emitB[gx];
            g = __expf(ev); gi = __expf(-ev);
        }
        g_lds[cc][j]  = g;
        gi_lds[cc][j] = gi;
    }
    __syncthreads();

    int lane = tid & 63, wv = tid >> 6;
    int cin = lane / 5;                  // 0..12
    int c = lane - cin * 5;
    int col = wv * 12 + cin;
    bool active = (cin < 12) && (col < 80);
    int base5 = (cin < 12) ? (cin * 5) : 0;

    float ed[K_], eT[C_];
    #pragma unroll
    for (int j = 0; j < K_; ++j) ed[j] = __expf(dur[c * K_ + j]);
    #pragma unroll
    for (int cc = 0; cc < C_; ++cc) eT[cc] = __expf(trans[cc * C_ + c]);

    float W[K_];
    #pragma unroll
    for (int j = 0; j < K_; ++j) W[j] = 0.0f;
    if (active) {
        int j0 = col / 5;
        int c0 = col - j0 * 5;
        if (c == c0) {
            float v = 1.0f;
            for (int j = 16 - j0; j < 16; ++j) v *= g_lds[c][j];
            #pragma unroll
            for (int j = 0; j < K_; ++j) if (j == j0) W[j] = v;
        }
    }

    float P = 1.0f, invP = 1.0f, z = 0.0f, Afin = 0.0f;
    float astep = 0.0f, A0v = 0.0f;
    int nfull = (L - 1) >> 4;            // 7..15
    int rem = L - (nfull << 4);          // 1..16
    int tl0 = 0;

    for (int bi = 0; bi < nfull; ++bi) {
        CHUNK_STEP(0,  tl0 + 0);  CHUNK_STEP(1,  tl0 + 1);
        CHUNK_STEP(2,  tl0 + 2);  CHUNK_STEP(3,  tl0 + 3);
        CHUNK_STEP(4,  tl0 + 4);  CHUNK_STEP(5,  tl0 + 5);
        CHUNK_STEP(6,  tl0 + 6);  CHUNK_STEP(7,  tl0 + 7);
        CHUNK_RENORM();
        CHUNK_STEP(8,  tl0 + 8);  CHUNK_STEP(9,  tl0 + 9);
        CHUNK_STEP(10, tl0 + 10); CHUNK_STEP(11, tl0 + 11);
        CHUNK_STEP(12, tl0 + 12); CHUNK_STEP(13, tl0 + 13);
        CHUNK_STEP(14, tl0 + 14); CHUNK_STEP(15, tl0 + 15);
        CHUNK_RENORM();
        tl0 += 16;
    }
    TAIL_STEP(0);  TAIL_STEP(1);  TAIL_STEP(2);  TAIL_STEP(3);
    TAIL_STEP(4);  TAIL_STEP(5);  TAIL_STEP(6);  TAIL_STEP(7);
    TAIL_STEP(8);  TAIL_STEP(9);  TAIL_STEP(10); TAIL_STEP(11);
    TAIL_STEP(12); TAIL_STEP(13); TAIL_STEP(14); TAIL_STEP(15);

    size_t cid = (size_t)b * NC_ + k;
    // epilogue: column-normalized M (non-last chunks) or R (last chunk); z' -> zsh
    if (active) {
        if (k == NC_ - 1) {
            #pragma unroll
            for (int cc2 = 0; cc2 < 1; ++cc2) { }   // keep structure simple
            Rout[(size_t)b * 400 + col * C_ + c] = Afin;
            if (c == 0) zsh[col] = z;
        } else {
            int pn = L & 15;
            float vals[K_];
            float lm = 0.0f;
            #pragma unroll
            for (int slot = 0; slot < K_; ++slot) {
                int j = (slot + pn) & 15;
                float pr = 1.0f;
                for (int i2 = 0; i2 < j; ++i2) pr *= gi_lds[c][16 + L - 1 - i2];
                float v = W[slot] * P * pr;
                vals[slot] = v;
                lm = fmaxf(lm, v);
            }
            float m0 = __shfl(lm, base5 + 0, 64);
            float m1 = __shfl(lm, base5 + 1, 64);
            float m2 = __shfl(lm, base5 + 2, 64);
            float m3 = __shfl(lm, base5 + 3, 64);
            float m4 = __shfl(lm, base5 + 4, 64);
            float cmax = fmaxf(fmaxf(fmaxf(m0, m1), fmaxf(m2, m3)), m4);
            float inv = (cmax > 0.0f) ? 1.0f / cmax : 0.0f;
            __hip_bfloat16* mb = Mout + cid * 6400 + (size_t)col * 80;
            #pragma unroll
            for (int slot = 0; slot < K_; ++slot) {
                int j = (slot + pn) & 15;
                mb[j * C_ + c] = __float2bfloat16(vals[slot] * inv);
            }
            if (c == 0) zsh[col] = (cmax > 0.0f) ? z + __logf(cmax) : -3.0e38f;
        }
    }
    __syncthreads();
    if (tid < 64) {
        float m = zsh[tid];
        if (tid < 16) m = fmaxf(m, zsh[tid + 64]);
        #pragma unroll
        for (int off = 32; off; off >>= 1) m = fmaxf(m, __shfl_xor(m, off, 64));
        if (tid == 0) zred = m;
    }
    __syncthreads();
    float zm = zred;
    if (tid == 0) Zmx[cid] = zm;
    if (active && c == 0) ezOut[cid * 80 + col] = __expf(zsh[col] - zm);
}

// ---------------- Kernel D: forward/backward vector chains (renorm every 4) ----------------
__global__ __launch_bounds__(320) void chain_kernel(
    const __hip_bfloat16* __restrict__ Mst, const float* __restrict__ ezZ,
    const float* __restrict__ Zmx, const float* __restrict__ Rst,
    const float* __restrict__ startv, float* __restrict__ Uvec,
    float* __restrict__ Xvec, float* __restrict__ Zu, float* __restrict__ Zx)
{
    __shared__ float Ml[2][80 * 82];
    __shared__ float vin[80], sv[80], part[4][80];
    __shared__ float red;
    int b = blockIdx.x >> 1;
    int dir = blockIdx.x & 1;
    int tid = threadIdx.x;
    float Z = 0.0f;
    int nmat = (dir == 0) ? NFW : (NC_ - 1 - NFW);   // 15 fwd, 16 bwd

    if (dir == 0) {
        if (tid < 80) vin[tid] = (tid < C_) ? __expf(startv[tid]) : 0.0f;
        __syncthreads();
    } else {
        size_t last = (size_t)b * NC_ + NC_ - 1;
        if (tid < 80) {
            const float* R = Rst + (size_t)b * 400 + (size_t)tid * C_;
            float rs = ((R[0] + R[1]) + (R[2] + R[3])) + R[4];
            sv[tid] = rs * ezZ[last * 80 + tid];
        }
        __syncthreads();
        if (tid < 64) {
            float m = sv[tid];
            if (tid < 16) m = fmaxf(m, sv[tid + 64]);
            #pragma unroll
            for (int o = 32; o; o >>= 1) m = fmaxf(m, __shfl_xor(m, o, 64));
            if (tid == 0) red = m;
        }
        __syncthreads();
        float rm = red;
        if (tid < 80) vin[tid] = sv[tid] / rm;
        Z = Zmx[b * NC_ + NC_ - 1] + __logf(rm);
        __syncthreads();
    }

    // stage first matrix
    int mk0 = (dir == 0) ? 0 : NC_ - 2;
    {
        const unsigned int* mg = (const unsigned int*)(Mst + (size_t)(b * NC_ + mk0) * 6400);
        #pragma unroll
        for (int i = 0; i < 10; ++i) {
            unsigned int u = mg[tid + 320 * i];
            int idx = (tid + 320 * i) * 2;
            int r = idx / 80, cc = idx - r * 80;
            Ml[0][r * 82 + cc]     = bf16lo(u);
            Ml[0][r * 82 + cc + 1] = bf16hi(u);
        }
    }
    __syncthreads();

    int cur = 0;
    int grp = tid / 80, r = tid - grp * 80;
    for (int it = 0; it < nmat; ++it) {
        int k  = (dir == 0) ? it : (NC_ - 2 - it);
        int kn = (dir == 0) ? k + 1 : k - 1;
        bool more = (it + 1 < nmat);
        size_t cid = (size_t)b * NC_ + k;

        unsigned int mu[10];
        if (more) {
            const unsigned int* mg = (const unsigned int*)(Mst + ((size_t)b * NC_ + kn) * 6400);
            #pragma unroll
            for (int i = 0; i < 10; ++i) mu[i] = mg[tid + 320 * i];
        }
        float ezv = 0.0f;
        if (tid < 80) {
            ezv = ezZ[cid * 80 + tid];
            sv[tid] = (dir == 0) ? vin[tid] * ezv : vin[tid];
        }
        __syncthreads();

        float p = 0.0f;
        if (dir == 0) {
            int q0 = grp * 20;
            #pragma unroll
            for (int i = 0; i < 20; ++i)
                p = fmaf(Ml[cur][(q0 + i) * 82 + r], sv[q0 + i], p);
        } else {
            int rowb = grp * 20;
            #pragma unroll
            for (int i = 0; i < 20; ++i)
                p = fmaf(Ml[cur][r * 82 + rowb + i], sv[rowb + i], p);
        }
        part[grp][r] = p;
        if (more) {
            #pragma unroll
            for (int i = 0; i < 10; ++i) {
                unsigned int u = mu[i];
                int idx = (tid + 320 * i) * 2;
                int rr = idx / 80, cc = idx - rr * 80;
                Ml[cur ^ 1][rr * 82 + cc]     = bf16lo(u);
                Ml[cur ^ 1][rr * 82 + cc + 1] = bf16hi(u);
            }
        }
        __syncthreads();

        Z += Zmx[cid];
        bool rn = ((it & 3) == 3) || (it == nmat - 1);
        if (tid < 80) {
            float nv = (part[0][tid] + part[1][tid]) + (part[2][tid] + part[3][tid]);
            if (dir == 1) nv *= ezv;
            if (rn) sv[tid] = nv; else vin[tid] = nv;
        }
        if (rn) {
            __syncthreads();
            if (tid < 64) {
                float m = sv[tid];
                if (tid < 16) m = fmaxf(m, sv[tid + 64]);
                #pragma unroll
                for (int o = 32; o; o >>= 1) m = fmaxf(m, __shfl_xor(m, o, 64));
                if (tid == 0) red = m;
            }
            __syncthreads();
            float rm = red;
            if (tid < 80) vin[tid] = sv[tid] / rm;
            Z += __logf(rm);
        }
        cur ^= 1;
    }

    if (dir == 0) {
        if (tid < 80) Xvec[b * 80 + tid] = vin[tid];
        if (tid == 0) Zx[b] = Z;
    } else {
        if (tid < 80) Uvec[b * 80 + tid] = vin[tid];
        if (tid == 0) Zu[b] = Z;
    }
}

// ---------------- Kernel E: meet -> partition ----------------
__global__ __launch_bounds__(512) void meet_kernel(
    const float* __restrict__ Uvec, const float* __restrict__ Xvec,
    const float* __restrict__ Zu, const float* __restrict__ Zx,
    float* __restrict__ partition)
{
    int tid = threadIdx.x;
    int b = tid >> 6, lane = tid & 63;
    float v = Uvec[b * 80 + lane] * Xvec[b * 80 + lane];
    if (lane < 16) v += Uvec[b * 80 + 64 + lane] * Xvec[b * 80 + 64 + lane];
    #pragma unroll
    for (int off = 32; off; off >>= 1) v += __shfl_xor(v, off, 64);
    if (lane == 0) partition[b] = Zu[b] + Zx[b] + __logf(v);
}

extern "C" void kernel_launch(void* const* d_in, const int* in_sizes, int n_in,
                              void* d_out, int out_size, void* d_ws, size_t ws_size,
                              hipStream_t stream) {
    (void)in_sizes; (void)n_in; (void)out_size; (void)ws_size;
    const float* seq    = (const float*)d_in[0];
    const int*   lens   = (const int*)  d_in[1];
    const float* W_enc  = (const float*)d_in[2];
    const float* b_enc  = (const float*)d_in[3];
    const float* W_proj = (const float*)d_in[4];
    const float* b_proj = (const float*)d_in[5];
    const float* trans  = (const float*)d_in[6];
    const float* startv = (const float*)d_in[7];
    const float* dur    = (const float*)d_in[8];

    float* out       = (float*)d_out;
    float* partition = out;
    float* cum       = out + B_;

    float* emitA = (float*)d_ws;                              // B*C*T f32
    float* emitB = emitA + (size_t)B_ * C_ * T_;              // B*C*T f32
    __hip_bfloat16* Mst = (__hip_bfloat16*)(emitB + (size_t)B_ * C_ * T_);  // B*NC*6400 bf16
    float* Rst = (float*)(Mst + (size_t)B_ * NC_ * 6400);     // B*400 f32 (last chunk only)
    float* ezS = Rst + (size_t)B_ * 400;                      // B*NC*80 f32
    float* Zmx = ezS + (size_t)B_ * NC_ * 80;                 // B*NC f32
    float* PA  = Zmx + (size_t)B_ * NC_;                      // 2*B*NTILE*C f32
    float* Uv  = PA  + 2 * B_ * NTILE * C_;                   // B*80
    float* Xv  = Uv  + B_ * 80;                               // B*80
    float* Zu  = Xv  + B_ * 80;                               // B
    float* Zx  = Zu  + B_;                                    // B

    encoder_kernel<<<512, 256, 0, stream>>>(seq, W_enc, b_enc, W_proj, b_proj, emitA, emitB, PA);
    chunk_kernel<<<B_ * NC_, 448, 0, stream>>>(emitA, emitB, lens, trans, dur, Mst, Rst, ezS, Zmx);
    cumwrite_kernel<<<B_ * C_ * NTILE, 64, 0, stream>>>(emitA, emitB, PA, cum);
    chain_kernel<<<16, 320, 0, stream>>>(Mst, ezS, Zmx, Rst, startv, Uv, Xv, Zu, Zx);
    meet_kernel<<<1, 512, 0, stream>>>(Uv, Xv, Zu, Zx, partition);
}